// Round 1
// baseline (510.079 us; speedup 1.0000x reference)
//
#include <hip/hip_runtime.h>
#include <stdint.h>

#define N_ANCH   100800
#define NUM_CLS  80
#define IMG_HW   1280
#define MAX_DETS 300
#define OUTSZ    224
#define CAND_CAP 4096

// d_out layout (float elements):
// [0,1200) boxes | [1200,1500) scores | [1500,1800) classes |
// [1800, 1800+45308928) crops | [45310728, 45311028) keep
#define OFF_BOXES   0
#define OFF_SCORES  1200
#define OFF_CLASSES 1500
#define OFF_CROPS   1800
#define CROPS_ELEMS (301 * 3 * 224 * 224)
#define OFF_KEEP    (OFF_CROPS + CROPS_ELEMS)

// scratch byte offsets inside crop region (base = (char*)d_out + OFF_CROPS*4)
#define SC_HIST   0         // u32[65536]
#define SC_CNT    262144    // u32
#define SC_THRESH 262148    // u32
#define SC_CAND   262208    // u64[4096]  (8-aligned: d_out 256-aligned, 7200+262208 % 8 == 0)
#define SC_KEYS   294976    // u32[100800]

__device__ __forceinline__ uint32_t fkey(float f) {
    uint32_t u = __float_as_uint(f);
    return (u & 0x80000000u) ? ~u : (u | 0x80000000u);
}
__device__ __forceinline__ float unfkey(uint32_t k) {
    uint32_t u = (k & 0x80000000u) ? (k & 0x7fffffffu) : ~k;
    return __uint_as_float(u);
}

// ---------------- K1: score / argmax / mask / histogram ----------------
__global__ void k_score(const float* __restrict__ rp, uint32_t* __restrict__ keys,
                        uint32_t* __restrict__ hist) {
    int a = blockIdx.x * 256 + threadIdx.x;
    if (a >= N_ANCH) return;
    float best = -3.402823466e38f;
    int bi = 0;
    for (int c = 0; c < NUM_CLS; ++c) {
        float v = rp[(5 + c) * N_ANCH + a];
        if (v > best) { best = v; bi = c; }
    }
    int cls = bi + 1;  // 1..80
    const unsigned long long AM =
        (1ULL << 1) | (1ULL << 2) | (1ULL << 3) | (1ULL << 4) | (1ULL << 6) |
        (1ULL << 8) | (1ULL << 17) | (1ULL << 18) | (1ULL << 44);
    bool m = (best > 0.1f) && (cls < 64) && ((AM >> cls) & 1ULL);
    uint32_t key = m ? fkey(best) : 0u;
    keys[a] = key;
    if (m) atomicAdd(&hist[key >> 16], 1u);
}

// ---------------- K2: find threshold bin (top-300 crossing) ----------------
__global__ void k_scan(const uint32_t* __restrict__ hist, uint32_t* __restrict__ thresh_out) {
    __shared__ uint32_t seg[256];
    int t = threadIdx.x;
    uint32_t s = 0;
    for (int k = 0; k < 256; ++k) s += hist[t * 256 + k];
    seg[t] = s;
    __syncthreads();
    if (t == 0) {
        uint32_t acc = 0;
        int bin = 0, sIdx = -1;
        for (int i = 255; i >= 0; --i) {
            if (acc + seg[i] >= (uint32_t)MAX_DETS) { sIdx = i; break; }
            acc += seg[i];
        }
        if (sIdx >= 0) {
            for (int b = sIdx * 256 + 255; b >= sIdx * 256; --b) {
                acc += hist[b];
                if (acc >= (uint32_t)MAX_DETS) { bin = b; break; }
            }
        }
        *thresh_out = (uint32_t)bin;
    }
}

// ---------------- K3: compact candidates above threshold ----------------
__global__ void k_compact(const uint32_t* __restrict__ keys, const uint32_t* __restrict__ thresh_p,
                          unsigned long long* __restrict__ cand, uint32_t* __restrict__ cnt) {
    int a = blockIdx.x * 256 + threadIdx.x;
    if (a >= N_ANCH) return;
    uint32_t key = keys[a];
    uint32_t tb = *thresh_p;
    if (key != 0u && (key >> 16) >= tb) {
        uint32_t pos = atomicAdd(cnt, 1u);
        if (pos < CAND_CAP)
            cand[pos] = ((unsigned long long)key << 32) | (uint32_t)(~(uint32_t)a);
    }
}

// ---------------- K4: sort + top300 + gather + NMS + small outputs ----------------
__global__ void __launch_bounds__(1024) k_select(const float* __restrict__ rp,
                                                 const unsigned long long* __restrict__ cand,
                                                 const uint32_t* __restrict__ cnt_p,
                                                 float* __restrict__ out) {
    __shared__ unsigned long long sb[CAND_CAP];      // 32 KB
    __shared__ float sbx[MAX_DETS][4];
    __shared__ float sscore[MAX_DETS];
    __shared__ int   scls[MAX_DETS];
    __shared__ uint32_t sup[MAX_DETS][10];           // suppression bitmatrix
    __shared__ uint32_t kw[10];                      // keep bit-words
    int t = threadIdx.x;
    int n = min((int)(*cnt_p), CAND_CAP);
    for (int i = t; i < CAND_CAP; i += 1024) sb[i] = (i < n) ? cand[i] : 0ull;
    __syncthreads();

    // bitonic sort, descending
    for (int k = 2; k <= CAND_CAP; k <<= 1) {
        for (int j = k >> 1; j > 0; j >>= 1) {
            for (int i = t; i < CAND_CAP; i += 1024) {
                int l = i ^ j;
                if (l > i) {
                    unsigned long long a = sb[i], b = sb[l];
                    bool up = ((i & k) == 0);
                    if ((up && a < b) || (!up && a > b)) { sb[i] = b; sb[l] = a; }
                }
            }
            __syncthreads();
        }
    }

    // zero suppression matrix + keep words
    for (int i = t; i < MAX_DETS * 10; i += 1024) ((uint32_t*)sup)[i] = 0u;
    if (t < 10) kw[t] = 0u;
    __syncthreads();

    // gather top-300 detections
    if (t < MAX_DETS) {
        unsigned long long key = sb[t];
        bool valid = (t < n) && (key != 0ull);
        float score = 0.f; int cls = 0;
        float b0 = 0.f, b1 = 0.f, b2 = 0.f, b3 = 0.f;
        if (valid) {
            uint32_t a = ~(uint32_t)(key & 0xffffffffull);
            score = unfkey((uint32_t)(key >> 32));
            float cx = rp[a], cy = rp[N_ANCH + a];
            float w = rp[2 * N_ANCH + a], h = rp[3 * N_ANCH + a];
            b0 = cx - w * 0.5f; b1 = cy - h * 0.5f;
            b2 = cx + w * 0.5f; b3 = cy + h * 0.5f;
            float best = -3.402823466e38f; int bi = 0;
            for (int c = 0; c < NUM_CLS; ++c) {
                float v = rp[(5 + c) * N_ANCH + a];
                if (v > best) { best = v; bi = c; }
            }
            cls = bi + 1;
            atomicOr(&kw[t >> 5], 1u << (t & 31));
        }
        sbx[t][0] = b0; sbx[t][1] = b1; sbx[t][2] = b2; sbx[t][3] = b3;
        sscore[t] = score; scls[t] = cls;
    }
    __syncthreads();

    // pairwise IoU -> suppression bits (j > i only)
    for (int p = t; p < MAX_DETS * MAX_DETS; p += 1024) {
        int i = p / MAX_DETS, j = p % MAX_DETS;
        if (j > i) {
            float ax1 = sbx[i][0], ay1 = sbx[i][1], ax2 = sbx[i][2], ay2 = sbx[i][3];
            float bx1 = sbx[j][0], by1 = sbx[j][1], bx2 = sbx[j][2], by2 = sbx[j][3];
            float areaA = (ax2 - ax1) * (ay2 - ay1);
            float areaB = (bx2 - bx1) * (by2 - by1);
            float ltx = fmaxf(ax1, bx1), lty = fmaxf(ay1, by1);
            float rbx = fminf(ax2, bx2), rby = fminf(ay2, by2);
            float iw = fmaxf(rbx - ltx, 0.f), ih = fmaxf(rby - lty, 0.f);
            float inter = iw * ih;
            float uni = areaA + areaB - inter;
            float iou = inter / fmaxf(uni, 1e-9f);
            if (iou > 0.45f) atomicOr(&sup[i][j >> 5], 1u << (j & 31));
        }
    }
    __syncthreads();

    // sequential greedy NMS over bit-words
    if (t == 0) {
        for (int i = 0; i < MAX_DETS; ++i) {
            if ((kw[i >> 5] >> (i & 31)) & 1u) {
                for (int w = 0; w < 10; ++w) kw[w] &= ~sup[i][w];
            }
        }
    }
    __syncthreads();

    // write small outputs
    if (t < MAX_DETS) {
        bool kp = (kw[t >> 5] >> (t & 31)) & 1u;
        out[OFF_BOXES + t * 4 + 0] = kp ? sbx[t][0] : 0.f;
        out[OFF_BOXES + t * 4 + 1] = kp ? sbx[t][1] : 0.f;
        out[OFF_BOXES + t * 4 + 2] = kp ? sbx[t][2] : 0.f;
        out[OFF_BOXES + t * 4 + 3] = kp ? sbx[t][3] : 0.f;
        out[OFF_SCORES + t]  = kp ? sscore[t] : 0.f;
        out[OFF_CLASSES + t] = kp ? (float)scls[t] : 0.f;
        out[OFF_KEEP + t]    = kp ? 1.f : 0.f;
    }
}

// ---------------- K5: full resize + ROI-align crops + normalize ----------------
__global__ void k_crops(const float* __restrict__ img, float* __restrict__ out) {
    int nc = blockIdx.y;            // 0..902 = n*3 + c
    int n = nc / 3, c = nc % 3;
    int pix = blockIdx.x * 256 + threadIdx.x;   // 0..50175 (exact)
    int oy = pix / OUTSZ, ox = pix % OUTSZ;
    const float meanv[3] = {0.485f, 0.456f, 0.406f};
    const float stdv[3]  = {0.229f, 0.224f, 0.225f};
    const float* ch = img + c * IMG_HW * IMG_HW;
    float val;
    if (n == 0) {
        // jax.image.resize linear, antialias=False: all samples interior
        float sx = ((float)ox + 0.5f) * (1280.0f / 224.0f) - 0.5f;
        float sy = ((float)oy + 0.5f) * (1280.0f / 224.0f) - 0.5f;
        int x0 = (int)floorf(sx), y0 = (int)floorf(sy);
        float lx = sx - (float)x0, ly = sy - (float)y0;
        int x1 = min(x0 + 1, IMG_HW - 1), y1 = min(y0 + 1, IMG_HW - 1);
        float v00 = ch[y0 * IMG_HW + x0], v01 = ch[y0 * IMG_HW + x1];
        float v10 = ch[y1 * IMG_HW + x0], v11 = ch[y1 * IMG_HW + x1];
        val = (v00 * (1.f - lx) + v01 * lx) * (1.f - ly) +
              (v10 * (1.f - lx) + v11 * lx) * ly;
    } else {
        float kp = out[OFF_KEEP + (n - 1)];
        if (kp == 0.f) {
            val = 0.f;   // reference zeroes crop BEFORE normalization
        } else {
            float x1b = out[OFF_BOXES + (n - 1) * 4 + 0];
            float y1b = out[OFF_BOXES + (n - 1) * 4 + 1];
            float x2b = out[OFF_BOXES + (n - 1) * 4 + 2];
            float y2b = out[OFF_BOXES + (n - 1) * 4 + 3];
            float gx = ((float)ox + 0.5f) / 224.0f;
            float gy = ((float)oy + 0.5f) / 224.0f;
            float xs = x1b - 0.5f + gx * (x2b - x1b);
            float ys = y1b - 0.5f + gy * (y2b - y1b);
            bool vx = (xs >= -1.0f) && (xs <= 1280.0f);
            bool vy = (ys >= -1.0f) && (ys <= 1280.0f);
            float xc = fminf(fmaxf(xs, 0.f), 1279.f);
            float yc = fminf(fmaxf(ys, 0.f), 1279.f);
            int x0 = (int)floorf(xc), y0 = (int)floorf(yc);
            int x1 = min(x0 + 1, IMG_HW - 1), y1 = min(y0 + 1, IMG_HW - 1);
            float lx = xc - (float)x0, ly = yc - (float)y0;
            float v00 = ch[y0 * IMG_HW + x0], v01 = ch[y0 * IMG_HW + x1];
            float v10 = ch[y1 * IMG_HW + x0], v11 = ch[y1 * IMG_HW + x1];
            val = (v00 * (1.f - lx) + v01 * lx) * (1.f - ly) +
                  (v10 * (1.f - lx) + v11 * lx) * ly;
            if (!(vx && vy)) val = 0.f;
        }
    }
    out[OFF_CROPS + nc * (OUTSZ * OUTSZ) + pix] = (val - meanv[c]) / stdv[c];
}

extern "C" void kernel_launch(void* const* d_in, const int* in_sizes, int n_in,
                              void* d_out, int out_size, void* d_ws, size_t ws_size,
                              hipStream_t stream) {
    (void)in_sizes; (void)n_in; (void)out_size; (void)d_ws; (void)ws_size;
    const float* rp  = (const float*)d_in[0];
    const float* img = (const float*)d_in[1];
    float* out = (float*)d_out;
    char* sbase = (char*)d_out + (size_t)OFF_CROPS * sizeof(float);
    uint32_t* hist = (uint32_t*)(sbase + SC_HIST);
    uint32_t* cnt  = (uint32_t*)(sbase + SC_CNT);
    uint32_t* thr  = (uint32_t*)(sbase + SC_THRESH);
    unsigned long long* cand = (unsigned long long*)(sbase + SC_CAND);
    uint32_t* keys = (uint32_t*)(sbase + SC_KEYS);

    hipMemsetAsync(sbase, 0, SC_CAND, stream);   // zero hist + cnt + thresh
    k_score<<<(N_ANCH + 255) / 256, 256, 0, stream>>>(rp, keys, hist);
    k_scan<<<1, 256, 0, stream>>>(hist, thr);
    k_compact<<<(N_ANCH + 255) / 256, 256, 0, stream>>>(keys, thr, cand, cnt);
    k_select<<<1, 1024, 0, stream>>>(rp, cand, cnt, out);
    dim3 grid(196, 903);
    k_crops<<<grid, 256, 0, stream>>>(img, out);
}

// Round 2
// 378.248 us; speedup vs baseline: 1.3485x; 1.3485x over previous
//
#include <hip/hip_runtime.h>
#include <stdint.h>

#define N_ANCH   100800
#define NUM_CLS  80
#define IMG_HW   1280
#define MAX_DETS 300
#define OUTSZ    224
#define CAND_CAP 4096

// d_out layout (float elements):
// [0,1200) boxes | [1200,1500) scores | [1500,1800) classes |
// [1800, 1800+45308928) crops | [45310728, 45311028) keep
#define OFF_BOXES   0
#define OFF_SCORES  1200
#define OFF_CLASSES 1500
#define OFF_CROPS   1800
#define CROPS_ELEMS (301 * 3 * 224 * 224)
#define OFF_KEEP    (OFF_CROPS + CROPS_ELEMS)

// scratch byte offsets inside crop region (base = (char*)d_out + OFF_CROPS*4)
// base is 7200 bytes from d_out => 16B aligned region start (7200 % 16 == 0... 7200/16=450 yes)
#define SC_HIST   0         // u32[65536]
#define SC_CNT    262144    // u32
#define SC_THRESH 262148    // u32
#define SC_CAND   262208    // u64[4096]   (7200+262208 divisible by 8)
#define SC_KEYS   294976    // u32[100800]
#define SC_CLS    698176    // u32[100800] (argmax class per anchor, from k_score)

__device__ __forceinline__ uint32_t fkey(float f) {
    uint32_t u = __float_as_uint(f);
    return (u & 0x80000000u) ? ~u : (u | 0x80000000u);
}
__device__ __forceinline__ float unfkey(uint32_t k) {
    uint32_t u = (k & 0x80000000u) ? (k & 0x7fffffffu) : ~k;
    return __uint_as_float(u);
}

// ---------------- K1: score / argmax / mask / histogram / class store ----------------
__global__ void k_score(const float* __restrict__ rp, uint32_t* __restrict__ keys,
                        uint32_t* __restrict__ hist, uint32_t* __restrict__ clsarr) {
    int a = blockIdx.x * 256 + threadIdx.x;
    if (a >= N_ANCH) return;
    float best = -3.402823466e38f;
    int bi = 0;
    for (int c = 0; c < NUM_CLS; ++c) {
        float v = rp[(5 + c) * N_ANCH + a];
        if (v > best) { best = v; bi = c; }
    }
    int cls = bi + 1;  // 1..80
    clsarr[a] = (uint32_t)cls;
    const unsigned long long AM =
        (1ULL << 1) | (1ULL << 2) | (1ULL << 3) | (1ULL << 4) | (1ULL << 6) |
        (1ULL << 8) | (1ULL << 17) | (1ULL << 18) | (1ULL << 44);
    bool m = (best > 0.1f) && (cls < 64) && ((AM >> cls) & 1ULL);
    uint32_t key = m ? fkey(best) : 0u;
    keys[a] = key;
    if (m) atomicAdd(&hist[key >> 16], 1u);
}

// ---------------- K2: find threshold bin (top-300 crossing) ----------------
__global__ void k_scan(const uint32_t* __restrict__ hist, uint32_t* __restrict__ thresh_out) {
    __shared__ uint32_t seg[256];
    int t = threadIdx.x;
    uint32_t s = 0;
    for (int k = 0; k < 256; ++k) s += hist[t * 256 + k];
    seg[t] = s;
    __syncthreads();
    if (t == 0) {
        uint32_t acc = 0;
        int bin = 0, sIdx = -1;
        for (int i = 255; i >= 0; --i) {
            if (acc + seg[i] >= (uint32_t)MAX_DETS) { sIdx = i; break; }
            acc += seg[i];
        }
        if (sIdx >= 0) {
            for (int b = sIdx * 256 + 255; b >= sIdx * 256; --b) {
                acc += hist[b];
                if (acc >= (uint32_t)MAX_DETS) { bin = b; break; }
            }
        }
        *thresh_out = (uint32_t)bin;
    }
}

// ---------------- K3: compact candidates above threshold ----------------
__global__ void k_compact(const uint32_t* __restrict__ keys, const uint32_t* __restrict__ thresh_p,
                          unsigned long long* __restrict__ cand, uint32_t* __restrict__ cnt) {
    int a = blockIdx.x * 256 + threadIdx.x;
    if (a >= N_ANCH) return;
    uint32_t key = keys[a];
    uint32_t tb = *thresh_p;
    if (key != 0u && (key >> 16) >= tb) {
        uint32_t pos = atomicAdd(cnt, 1u);
        if (pos < CAND_CAP)
            cand[pos] = ((unsigned long long)key << 32) | (uint32_t)(~(uint32_t)a);
    }
}

// ---------------- K4: sort + top300 + gather + NMS + small outputs ----------------
__global__ void __launch_bounds__(1024) k_select(const float* __restrict__ rp,
                                                 const uint32_t* __restrict__ clsarr,
                                                 const unsigned long long* __restrict__ cand,
                                                 const uint32_t* __restrict__ cnt_p,
                                                 float* __restrict__ out) {
    __shared__ unsigned long long sb[CAND_CAP];              // 32 KB
    __shared__ float sbx[MAX_DETS][4];
    __shared__ float sscore[MAX_DETS];
    __shared__ int   scls[MAX_DETS];
    __shared__ __align__(8) uint32_t sup[MAX_DETS][10];      // suppression bitmatrix (rows 40B => 8-aligned)
    __shared__ __align__(8) uint32_t kw[10];                 // keep bit-words
    __shared__ __align__(8) uint32_t rnz[10];                // "row has any suppression" bits
    int t = threadIdx.x;
    int n = min((int)(*cnt_p), CAND_CAP);

    // sort size: next pow2 >= n, min 1024 (histogram cut keeps n small)
    int S = 1024;
    while (S < n) S <<= 1;

    for (int i = t; i < S; i += 1024) sb[i] = (i < n) ? cand[i] : 0ull;
    __syncthreads();

    // bitonic sort, descending
    for (int k = 2; k <= S; k <<= 1) {
        for (int j = k >> 1; j > 0; j >>= 1) {
            for (int i = t; i < S; i += 1024) {
                int l = i ^ j;
                if (l > i) {
                    unsigned long long a = sb[i], b = sb[l];
                    bool up = ((i & k) == 0);
                    if ((up && a < b) || (!up && a > b)) { sb[i] = b; sb[l] = a; }
                }
            }
            __syncthreads();
        }
    }

    // zero suppression matrix + keep words + rnz
    for (int i = t; i < MAX_DETS * 10; i += 1024) ((uint32_t*)sup)[i] = 0u;
    if (t < 10) { kw[t] = 0u; rnz[t] = 0u; }
    __syncthreads();

    // gather top-300 detections (class from clsarr — no 80-logit re-gather)
    if (t < MAX_DETS) {
        unsigned long long key = sb[t];
        bool valid = (t < n) && (key != 0ull);
        float score = 0.f; int cls = 0;
        float b0 = 0.f, b1 = 0.f, b2 = 0.f, b3 = 0.f;
        if (valid) {
            uint32_t a = ~(uint32_t)(key & 0xffffffffull);
            score = unfkey((uint32_t)(key >> 32));
            float cx = rp[a], cy = rp[N_ANCH + a];
            float w = rp[2 * N_ANCH + a], h = rp[3 * N_ANCH + a];
            b0 = cx - w * 0.5f; b1 = cy - h * 0.5f;
            b2 = cx + w * 0.5f; b3 = cy + h * 0.5f;
            cls = (int)clsarr[a];
            atomicOr(&kw[t >> 5], 1u << (t & 31));
        }
        sbx[t][0] = b0; sbx[t][1] = b1; sbx[t][2] = b2; sbx[t][3] = b3;
        sscore[t] = score; scls[t] = cls;
    }
    __syncthreads();

    // pairwise IoU -> suppression bits (j > i only; whole waves with j<=i skip via execz)
    for (int p = t; p < MAX_DETS * MAX_DETS; p += 1024) {
        int i = p / MAX_DETS, j = p % MAX_DETS;
        if (j > i) {
            float ax1 = sbx[i][0], ay1 = sbx[i][1], ax2 = sbx[i][2], ay2 = sbx[i][3];
            float bx1 = sbx[j][0], by1 = sbx[j][1], bx2 = sbx[j][2], by2 = sbx[j][3];
            float areaA = (ax2 - ax1) * (ay2 - ay1);
            float areaB = (bx2 - bx1) * (by2 - by1);
            float ltx = fmaxf(ax1, bx1), lty = fmaxf(ay1, by1);
            float rbx = fminf(ax2, bx2), rby = fminf(ay2, by2);
            float iw = fmaxf(rbx - ltx, 0.f), ih = fmaxf(rby - lty, 0.f);
            float inter = iw * ih;
            float uni = areaA + areaB - inter;
            float iou = inter / fmaxf(uni, 1e-9f);
            if (iou > 0.45f) {
                atomicOr(&sup[i][j >> 5], 1u << (j & 31));
                atomicOr(&rnz[i >> 5], 1u << (i & 31));
            }
        }
    }
    __syncthreads();

    // sequential greedy NMS: keep-mask in registers; only touch LDS for nonzero rows
    if (t == 0) {
        unsigned long long kwr[5], rnzr[5];
        const unsigned long long* kq = (const unsigned long long*)kw;
        const unsigned long long* rq = (const unsigned long long*)rnz;
        #pragma unroll
        for (int w = 0; w < 5; ++w) { kwr[w] = kq[w]; rnzr[w] = rq[w]; }
        #pragma unroll
        for (int s = 0; s < 5; ++s) {
            int lim = (s == 4) ? (MAX_DETS - 4 * 64) : 64;
            for (int i2 = 0; i2 < lim; ++i2) {
                if (((kwr[s] >> i2) & 1ull) && ((rnzr[s] >> i2) & 1ull)) {
                    int i = s * 64 + i2;
                    const unsigned long long* row = (const unsigned long long*)&sup[i][0];
                    unsigned long long r0 = row[0], r1 = row[1], r2 = row[2],
                                       r3 = row[3], r4 = row[4];
                    kwr[0] &= ~r0; kwr[1] &= ~r1; kwr[2] &= ~r2;
                    kwr[3] &= ~r3; kwr[4] &= ~r4;
                }
            }
        }
        unsigned long long* kqo = (unsigned long long*)kw;
        #pragma unroll
        for (int w = 0; w < 5; ++w) kqo[w] = kwr[w];
    }
    __syncthreads();

    // write small outputs
    if (t < MAX_DETS) {
        bool kp = (kw[t >> 5] >> (t & 31)) & 1u;
        out[OFF_BOXES + t * 4 + 0] = kp ? sbx[t][0] : 0.f;
        out[OFF_BOXES + t * 4 + 1] = kp ? sbx[t][1] : 0.f;
        out[OFF_BOXES + t * 4 + 2] = kp ? sbx[t][2] : 0.f;
        out[OFF_BOXES + t * 4 + 3] = kp ? sbx[t][3] : 0.f;
        out[OFF_SCORES + t]  = kp ? sscore[t] : 0.f;
        out[OFF_CLASSES + t] = kp ? (float)scls[t] : 0.f;
        out[OFF_KEEP + t]    = kp ? 1.f : 0.f;
    }
}

// ---------------- K5: full resize + ROI-align crops + normalize (float4 stores) ----------------
__device__ __forceinline__ float bilerp(const float* __restrict__ ch, float xc, float yc) {
    int x0 = (int)floorf(xc), y0 = (int)floorf(yc);
    int x1 = min(x0 + 1, IMG_HW - 1), y1 = min(y0 + 1, IMG_HW - 1);
    float lx = xc - (float)x0, ly = yc - (float)y0;
    float v00 = ch[y0 * IMG_HW + x0], v01 = ch[y0 * IMG_HW + x1];
    float v10 = ch[y1 * IMG_HW + x0], v11 = ch[y1 * IMG_HW + x1];
    return (v00 * (1.f - lx) + v01 * lx) * (1.f - ly) +
           (v10 * (1.f - lx) + v11 * lx) * ly;
}

__global__ void k_crops(const float* __restrict__ img, float* __restrict__ out) {
    int nc = blockIdx.y;            // 0..902 = n*3 + c
    int n = nc / 3, c = nc % 3;
    int q = blockIdx.x * 256 + threadIdx.x;   // 0..12543 (exact: 49*256)
    int oy = q / (OUTSZ / 4);
    int ox0 = (q % (OUTSZ / 4)) * 4;
    const float meanv[3] = {0.485f, 0.456f, 0.406f};
    const float stdv[3]  = {0.229f, 0.224f, 0.225f};
    float mean = meanv[c], rstd = 1.0f / stdv[c];
    const float* ch = img + c * IMG_HW * IMG_HW;
    float4 v;
    if (n == 0) {
        // jax.image.resize linear, antialias=False: all samples interior
        float sy = ((float)oy + 0.5f) * (1280.0f / 224.0f) - 0.5f;
        float r[4];
        #pragma unroll
        for (int k = 0; k < 4; ++k) {
            float sx = ((float)(ox0 + k) + 0.5f) * (1280.0f / 224.0f) - 0.5f;
            r[k] = (bilerp(ch, sx, sy) - mean) * rstd;
        }
        v = make_float4(r[0], r[1], r[2], r[3]);
    } else {
        float kp = out[OFF_KEEP + (n - 1)];
        if (kp == 0.f) {
            float z = (0.f - mean) * rstd;   // reference zeroes crop BEFORE normalization
            v = make_float4(z, z, z, z);
        } else {
            float x1b = out[OFF_BOXES + (n - 1) * 4 + 0];
            float y1b = out[OFF_BOXES + (n - 1) * 4 + 1];
            float x2b = out[OFF_BOXES + (n - 1) * 4 + 2];
            float y2b = out[OFF_BOXES + (n - 1) * 4 + 3];
            float gy = ((float)oy + 0.5f) / 224.0f;
            float ys = y1b - 0.5f + gy * (y2b - y1b);
            bool vy = (ys >= -1.0f) && (ys <= 1280.0f);
            float yc = fminf(fmaxf(ys, 0.f), 1279.f);
            float r[4];
            #pragma unroll
            for (int k = 0; k < 4; ++k) {
                float gx = ((float)(ox0 + k) + 0.5f) / 224.0f;
                float xs = x1b - 0.5f + gx * (x2b - x1b);
                bool vx = (xs >= -1.0f) && (xs <= 1280.0f);
                float xc = fminf(fmaxf(xs, 0.f), 1279.f);
                float val = bilerp(ch, xc, yc);
                if (!(vx && vy)) val = 0.f;
                r[k] = (val - mean) * rstd;
            }
            v = make_float4(r[0], r[1], r[2], r[3]);
        }
    }
    *(float4*)(out + OFF_CROPS + (size_t)nc * (OUTSZ * OUTSZ) + oy * OUTSZ + ox0) = v;
}

extern "C" void kernel_launch(void* const* d_in, const int* in_sizes, int n_in,
                              void* d_out, int out_size, void* d_ws, size_t ws_size,
                              hipStream_t stream) {
    (void)in_sizes; (void)n_in; (void)out_size; (void)d_ws; (void)ws_size;
    const float* rp  = (const float*)d_in[0];
    const float* img = (const float*)d_in[1];
    float* out = (float*)d_out;
    char* sbase = (char*)d_out + (size_t)OFF_CROPS * sizeof(float);
    uint32_t* hist = (uint32_t*)(sbase + SC_HIST);
    uint32_t* cnt  = (uint32_t*)(sbase + SC_CNT);
    uint32_t* thr  = (uint32_t*)(sbase + SC_THRESH);
    unsigned long long* cand = (unsigned long long*)(sbase + SC_CAND);
    uint32_t* keys = (uint32_t*)(sbase + SC_KEYS);
    uint32_t* clsa = (uint32_t*)(sbase + SC_CLS);

    hipMemsetAsync(sbase, 0, SC_CAND, stream);   // zero hist + cnt + thresh
    k_score<<<(N_ANCH + 255) / 256, 256, 0, stream>>>(rp, keys, hist, clsa);
    k_scan<<<1, 256, 0, stream>>>(hist, thr);
    k_compact<<<(N_ANCH + 255) / 256, 256, 0, stream>>>(keys, thr, cand, cnt);
    k_select<<<1, 1024, 0, stream>>>(rp, clsa, cand, cnt, out);
    dim3 grid(49, 903);
    k_crops<<<grid, 256, 0, stream>>>(img, out);
}

// Round 3
// 371.088 us; speedup vs baseline: 1.3745x; 1.0193x over previous
//
#include <hip/hip_runtime.h>
#include <stdint.h>

#define N_ANCH   100800
#define NUM_CLS  80
#define IMG_HW   1280
#define MAX_DETS 300
#define OUTSZ    224
#define CAND_CAP 4096

// d_out layout (float elements):
// [0,1200) boxes | [1200,1500) scores | [1500,1800) classes |
// [1800, 1800+45308928) crops | [45310728, 45311028) keep
#define OFF_BOXES   0
#define OFF_SCORES  1200
#define OFF_CLASSES 1500
#define OFF_CROPS   1800
#define CROPS_ELEMS (301 * 3 * 224 * 224)
#define OFF_KEEP    (OFF_CROPS + CROPS_ELEMS)

// scratch byte offsets inside crop region (base = (char*)d_out + OFF_CROPS*4)
#define SC_HIST   0         // u32[65536]
#define SC_CNT    262144    // u32
#define SC_THRESH 262148    // u32
#define SC_CAND   262208    // u64[4096]
#define SC_KEYS   294976    // u32[100800]
#define SC_CLS    698176    // u32[100800]

typedef float f32x4 __attribute__((ext_vector_type(4)));

__device__ __forceinline__ uint32_t fkey(float f) {
    uint32_t u = __float_as_uint(f);
    return (u & 0x80000000u) ? ~u : (u | 0x80000000u);
}
__device__ __forceinline__ float unfkey(uint32_t k) {
    uint32_t u = (k & 0x80000000u) ? (k & 0x7fffffffu) : ~k;
    return __uint_as_float(u);
}

// ---------------- K1: score / argmax / mask / histogram / class store (4 anchors/thread) ----------------
__global__ void k_score(const float* __restrict__ rp, uint32_t* __restrict__ keys,
                        uint32_t* __restrict__ hist, uint32_t* __restrict__ clsarr) {
    int a4 = (blockIdx.x * 256 + threadIdx.x) * 4;
    if (a4 >= N_ANCH) return;
    float best[4] = {-3.402823466e38f, -3.402823466e38f, -3.402823466e38f, -3.402823466e38f};
    int bi[4] = {0, 0, 0, 0};
    for (int c = 0; c < NUM_CLS; ++c) {
        float4 v = *(const float4*)&rp[(5 + c) * N_ANCH + a4];
        if (v.x > best[0]) { best[0] = v.x; bi[0] = c; }
        if (v.y > best[1]) { best[1] = v.y; bi[1] = c; }
        if (v.z > best[2]) { best[2] = v.z; bi[2] = c; }
        if (v.w > best[3]) { best[3] = v.w; bi[3] = c; }
    }
    const unsigned long long AM =
        (1ULL << 1) | (1ULL << 2) | (1ULL << 3) | (1ULL << 4) | (1ULL << 6) |
        (1ULL << 8) | (1ULL << 17) | (1ULL << 18) | (1ULL << 44);
    uint32_t kv[4], cv[4];
    #pragma unroll
    for (int k = 0; k < 4; ++k) {
        int cls = bi[k] + 1;  // 1..80
        cv[k] = (uint32_t)cls;
        bool m = (best[k] > 0.1f) && (cls < 64) && ((AM >> cls) & 1ULL);
        kv[k] = m ? fkey(best[k]) : 0u;
    }
    *(uint4*)&keys[a4]   = make_uint4(kv[0], kv[1], kv[2], kv[3]);
    *(uint4*)&clsarr[a4] = make_uint4(cv[0], cv[1], cv[2], cv[3]);
    #pragma unroll
    for (int k = 0; k < 4; ++k)
        if (kv[k]) atomicAdd(&hist[kv[k] >> 16], 1u);
}

// ---------------- K2: find threshold bin (top-300 crossing) ----------------
__global__ void k_scan(const uint32_t* __restrict__ hist, uint32_t* __restrict__ thresh_out) {
    __shared__ uint32_t seg[256];
    int t = threadIdx.x;
    uint32_t s = 0;
    for (int k = 0; k < 256; ++k) s += hist[t * 256 + k];
    seg[t] = s;
    __syncthreads();
    if (t == 0) {
        uint32_t acc = 0;
        int bin = 0, sIdx = -1;
        for (int i = 255; i >= 0; --i) {
            if (acc + seg[i] >= (uint32_t)MAX_DETS) { sIdx = i; break; }
            acc += seg[i];
        }
        if (sIdx >= 0) {
            for (int b = sIdx * 256 + 255; b >= sIdx * 256; --b) {
                acc += hist[b];
                if (acc >= (uint32_t)MAX_DETS) { bin = b; break; }
            }
        }
        *thresh_out = (uint32_t)bin;
    }
}

// ---------------- K3: compact candidates above threshold (4 anchors/thread) ----------------
__global__ void k_compact(const uint32_t* __restrict__ keys, const uint32_t* __restrict__ thresh_p,
                          unsigned long long* __restrict__ cand, uint32_t* __restrict__ cnt) {
    int a4 = (blockIdx.x * 256 + threadIdx.x) * 4;
    if (a4 >= N_ANCH) return;
    uint4 kv = *(const uint4*)&keys[a4];
    uint32_t tb = *thresh_p;
    uint32_t ks[4] = {kv.x, kv.y, kv.z, kv.w};
    #pragma unroll
    for (int k = 0; k < 4; ++k) {
        uint32_t key = ks[k];
        if (key != 0u && (key >> 16) >= tb) {
            uint32_t pos = atomicAdd(cnt, 1u);
            if (pos < CAND_CAP) {
                uint32_t a = (uint32_t)(a4 + k);
                cand[pos] = ((unsigned long long)key << 32) | (uint32_t)(~a);
            }
        }
    }
}

// ---------------- K4: rank-select top300 + gather + NMS + small outputs ----------------
__global__ void __launch_bounds__(1024) k_select(const float* __restrict__ rp,
                                                 const uint32_t* __restrict__ clsarr,
                                                 const unsigned long long* __restrict__ cand,
                                                 const uint32_t* __restrict__ cnt_p,
                                                 float* __restrict__ out) {
    __shared__ unsigned long long sb[CAND_CAP];              // 32 KB candidate keys
    __shared__ unsigned long long top[MAX_DETS];             // rank -> key
    __shared__ float sbx[MAX_DETS][4];
    __shared__ float sscore[MAX_DETS];
    __shared__ int   scls[MAX_DETS];
    __shared__ __align__(8) uint32_t sup[MAX_DETS][10];      // suppression bitmatrix
    __shared__ __align__(8) uint32_t kw[10];                 // keep bit-words
    __shared__ __align__(8) uint32_t rnz[10];                // "row has suppression" bits
    int t = threadIdx.x;
    int n = min((int)(*cnt_p), CAND_CAP);

    for (int i = t; i < n; i += 1024) sb[i] = cand[i];
    if (t < MAX_DETS) top[t] = 0ull;
    __syncthreads();

    // rank selection: keys are unique ((score<<32)|~idx), rank = exact descending position
    for (int i = t; i < n; i += 1024) {
        unsigned long long key = sb[i];
        int rank = 0;
        for (int j = 0; j < n; ++j) rank += (sb[j] > key) ? 1 : 0;
        if (rank < MAX_DETS) top[rank] = key;
    }
    __syncthreads();

    // zero suppression matrix + keep words + rnz
    for (int i = t; i < MAX_DETS * 10; i += 1024) ((uint32_t*)sup)[i] = 0u;
    if (t < 10) { kw[t] = 0u; rnz[t] = 0u; }
    __syncthreads();

    // gather top-300 detections
    if (t < MAX_DETS) {
        unsigned long long key = top[t];
        bool valid = (key != 0ull);
        float score = 0.f; int cls = 0;
        float b0 = 0.f, b1 = 0.f, b2 = 0.f, b3 = 0.f;
        if (valid) {
            uint32_t a = ~(uint32_t)(key & 0xffffffffull);
            score = unfkey((uint32_t)(key >> 32));
            float cx = rp[a], cy = rp[N_ANCH + a];
            float w = rp[2 * N_ANCH + a], h = rp[3 * N_ANCH + a];
            b0 = cx - w * 0.5f; b1 = cy - h * 0.5f;
            b2 = cx + w * 0.5f; b3 = cy + h * 0.5f;
            cls = (int)clsarr[a];
            atomicOr(&kw[t >> 5], 1u << (t & 31));
        }
        sbx[t][0] = b0; sbx[t][1] = b1; sbx[t][2] = b2; sbx[t][3] = b3;
        sscore[t] = score; scls[t] = cls;
    }
    __syncthreads();

    // pairwise IoU -> suppression bits (j > i only)
    for (int p = t; p < MAX_DETS * MAX_DETS; p += 1024) {
        int i = p / MAX_DETS, j = p % MAX_DETS;
        if (j > i) {
            float ax1 = sbx[i][0], ay1 = sbx[i][1], ax2 = sbx[i][2], ay2 = sbx[i][3];
            float bx1 = sbx[j][0], by1 = sbx[j][1], bx2 = sbx[j][2], by2 = sbx[j][3];
            float areaA = (ax2 - ax1) * (ay2 - ay1);
            float areaB = (bx2 - bx1) * (by2 - by1);
            float ltx = fmaxf(ax1, bx1), lty = fmaxf(ay1, by1);
            float rbx = fminf(ax2, bx2), rby = fminf(ay2, by2);
            float iw = fmaxf(rbx - ltx, 0.f), ih = fmaxf(rby - lty, 0.f);
            float inter = iw * ih;
            float uni = areaA + areaB - inter;
            float iou = inter / fmaxf(uni, 1e-9f);
            if (iou > 0.45f) {
                atomicOr(&sup[i][j >> 5], 1u << (j & 31));
                atomicOr(&rnz[i >> 5], 1u << (i & 31));
            }
        }
    }
    __syncthreads();

    // sequential greedy NMS: keep-mask in registers; only touch LDS for nonzero rows
    if (t == 0) {
        unsigned long long kwr[5], rnzr[5];
        const unsigned long long* kq = (const unsigned long long*)kw;
        const unsigned long long* rq = (const unsigned long long*)rnz;
        #pragma unroll
        for (int w = 0; w < 5; ++w) { kwr[w] = kq[w]; rnzr[w] = rq[w]; }
        #pragma unroll
        for (int s = 0; s < 5; ++s) {
            int lim = (s == 4) ? (MAX_DETS - 4 * 64) : 64;
            for (int i2 = 0; i2 < lim; ++i2) {
                if (((kwr[s] >> i2) & 1ull) && ((rnzr[s] >> i2) & 1ull)) {
                    int i = s * 64 + i2;
                    const unsigned long long* row = (const unsigned long long*)&sup[i][0];
                    unsigned long long r0 = row[0], r1 = row[1], r2 = row[2],
                                       r3 = row[3], r4 = row[4];
                    kwr[0] &= ~r0; kwr[1] &= ~r1; kwr[2] &= ~r2;
                    kwr[3] &= ~r3; kwr[4] &= ~r4;
                }
            }
        }
        unsigned long long* kqo = (unsigned long long*)kw;
        #pragma unroll
        for (int w = 0; w < 5; ++w) kqo[w] = kwr[w];
    }
    __syncthreads();

    // write small outputs
    if (t < MAX_DETS) {
        bool kp = (kw[t >> 5] >> (t & 31)) & 1u;
        out[OFF_BOXES + t * 4 + 0] = kp ? sbx[t][0] : 0.f;
        out[OFF_BOXES + t * 4 + 1] = kp ? sbx[t][1] : 0.f;
        out[OFF_BOXES + t * 4 + 2] = kp ? sbx[t][2] : 0.f;
        out[OFF_BOXES + t * 4 + 3] = kp ? sbx[t][3] : 0.f;
        out[OFF_SCORES + t]  = kp ? sscore[t] : 0.f;
        out[OFF_CLASSES + t] = kp ? (float)scls[t] : 0.f;
        out[OFF_KEEP + t]    = kp ? 1.f : 0.f;
    }
}

// ---------------- K5: full resize + ROI-align crops + normalize (nt float4 stores) ----------------
__device__ __forceinline__ float bilerp(const float* __restrict__ ch, float xc, float yc) {
    int x0 = (int)floorf(xc), y0 = (int)floorf(yc);
    int x1 = min(x0 + 1, IMG_HW - 1), y1 = min(y0 + 1, IMG_HW - 1);
    float lx = xc - (float)x0, ly = yc - (float)y0;
    float v00 = ch[y0 * IMG_HW + x0], v01 = ch[y0 * IMG_HW + x1];
    float v10 = ch[y1 * IMG_HW + x0], v11 = ch[y1 * IMG_HW + x1];
    return (v00 * (1.f - lx) + v01 * lx) * (1.f - ly) +
           (v10 * (1.f - lx) + v11 * lx) * ly;
}

__global__ void k_crops(const float* __restrict__ img, float* __restrict__ out) {
    int nc = blockIdx.y;            // 0..902 = n*3 + c
    int n = nc / 3, c = nc % 3;
    int q = blockIdx.x * 256 + threadIdx.x;   // 0..12543 (exact: 49*256)
    int oy = q / (OUTSZ / 4);
    int ox0 = (q % (OUTSZ / 4)) * 4;
    const float meanv[3] = {0.485f, 0.456f, 0.406f};
    const float stdv[3]  = {0.229f, 0.224f, 0.225f};
    float mean = meanv[c], rstd = 1.0f / stdv[c];
    const float* ch = img + c * IMG_HW * IMG_HW;
    f32x4 v;
    if (n == 0) {
        // jax.image.resize linear, antialias=False: all samples interior
        float sy = ((float)oy + 0.5f) * (1280.0f / 224.0f) - 0.5f;
        #pragma unroll
        for (int k = 0; k < 4; ++k) {
            float sx = ((float)(ox0 + k) + 0.5f) * (1280.0f / 224.0f) - 0.5f;
            v[k] = (bilerp(ch, sx, sy) - mean) * rstd;
        }
    } else {
        float kp = out[OFF_KEEP + (n - 1)];
        if (kp == 0.f) {
            float z = (0.f - mean) * rstd;   // reference zeroes crop BEFORE normalization
            v = (f32x4){z, z, z, z};
        } else {
            float x1b = out[OFF_BOXES + (n - 1) * 4 + 0];
            float y1b = out[OFF_BOXES + (n - 1) * 4 + 1];
            float x2b = out[OFF_BOXES + (n - 1) * 4 + 2];
            float y2b = out[OFF_BOXES + (n - 1) * 4 + 3];
            float gy = ((float)oy + 0.5f) / 224.0f;
            float ys = y1b - 0.5f + gy * (y2b - y1b);
            bool vy = (ys >= -1.0f) && (ys <= 1280.0f);
            float yc = fminf(fmaxf(ys, 0.f), 1279.f);
            #pragma unroll
            for (int k = 0; k < 4; ++k) {
                float gx = ((float)(ox0 + k) + 0.5f) / 224.0f;
                float xs = x1b - 0.5f + gx * (x2b - x1b);
                bool vx = (xs >= -1.0f) && (xs <= 1280.0f);
                float xc = fminf(fmaxf(xs, 0.f), 1279.f);
                float val = bilerp(ch, xc, yc);
                if (!(vx && vy)) val = 0.f;
                v[k] = (val - mean) * rstd;
            }
        }
    }
    f32x4* dst = (f32x4*)(out + OFF_CROPS + (size_t)nc * (OUTSZ * OUTSZ) + oy * OUTSZ + ox0);
    __builtin_nontemporal_store(v, dst);
}

extern "C" void kernel_launch(void* const* d_in, const int* in_sizes, int n_in,
                              void* d_out, int out_size, void* d_ws, size_t ws_size,
                              hipStream_t stream) {
    (void)in_sizes; (void)n_in; (void)out_size; (void)d_ws; (void)ws_size;
    const float* rp  = (const float*)d_in[0];
    const float* img = (const float*)d_in[1];
    float* out = (float*)d_out;
    char* sbase = (char*)d_out + (size_t)OFF_CROPS * sizeof(float);
    uint32_t* hist = (uint32_t*)(sbase + SC_HIST);
    uint32_t* cnt  = (uint32_t*)(sbase + SC_CNT);
    uint32_t* thr  = (uint32_t*)(sbase + SC_THRESH);
    unsigned long long* cand = (unsigned long long*)(sbase + SC_CAND);
    uint32_t* keys = (uint32_t*)(sbase + SC_KEYS);
    uint32_t* clsa = (uint32_t*)(sbase + SC_CLS);

    hipMemsetAsync(sbase, 0, SC_CAND, stream);   // zero hist + cnt + thresh
    k_score<<<(N_ANCH / 4 + 255) / 256, 256, 0, stream>>>(rp, keys, hist, clsa);
    k_scan<<<1, 256, 0, stream>>>(hist, thr);
    k_compact<<<(N_ANCH / 4 + 255) / 256, 256, 0, stream>>>(keys, thr, cand, cnt);
    k_select<<<1, 1024, 0, stream>>>(rp, clsa, cand, cnt, out);
    dim3 grid(49, 903);
    k_crops<<<grid, 256, 0, stream>>>(img, out);
}